// Round 7
// baseline (140.693 us; speedup 1.0000x reference)
//
#include <hip/hip_runtime.h>
#include <cstdint>
#include <cstddef>

// SelfAttention: B=8, C=256, H=W=32, HEADS=8, hd=32, N=HW=1024
// Pipeline (all bf16 MFMA 16x16x32, fp32 accum):
//   prep:  W[4] fp32->bf16 ; x [b,c,p] fp32 -> xt [b,p,c] bf16 (LDS transpose)
//   qkv :  q,k -> [b,h,n,d] bf16 ; v -> [b,c,p'] bf16, p' k-interleaved per 32-tile
//   attn:  flash, static-max softmax (2^(s*scale*log2e - 16), exact after 1/l),
//          l via MFMA ones-B, same-iteration P LDS round-trip (R2/R6-proven).
//          Wave owns 32 q rows (2 frags). Grid (bh, nchunk) so all 8 blocks of
//          one bh land on XCD bh%8 (linear id = bh + 64*y -> id%8 = bh%8):
//          K/V stays L2-resident per XCD (R2 showed 36MB fetch vs 12MB data).
//          Depth-2 K/V register prefetch to cover L2 latency.
//   mproj: final projection -> d_out fp32
// ws layout: xt 4MB | Wb 512KB | qt 4MB | kt 4MB | vt 4MB | at 4MB  = 20.5 MB

#define NB 8
#define NC 256
#define NP 1024
#define NHD 8
#define HD 32

typedef short bf16x8 __attribute__((ext_vector_type(8)));
typedef float f32x4 __attribute__((ext_vector_type(4)));

// scale * log2(e) : softmax(s/sqrt(32)) computed as 2^(s*SCLLOG - 16)
#define SCLLOG 0.25505654356918f

// hardware packed fp32->bf16 (RNE): D.lo = bf16(a), D.hi = bf16(b)
__device__ __forceinline__ unsigned cvt_pk_bf16(float a, float b) {
  unsigned r;
  asm("v_cvt_pk_bf16_f32 %0, %1, %2" : "=v"(r) : "v"(a), "v"(b));
  return r;
}
__device__ __forceinline__ unsigned short f2b1(float a) {
  return (unsigned short)cvt_pk_bf16(a, a);
}

// ---------------- prep: weight cvt + x transpose ----------------
__global__ __launch_bounds__(256) void prep_kernel(
    const float* __restrict__ Wq, const float* __restrict__ Wk,
    const float* __restrict__ Wv, const float* __restrict__ Wm,
    const float* __restrict__ x, unsigned short* __restrict__ Wb,
    unsigned short* __restrict__ xt) {
  __shared__ float sx[64][65];
  int bx = blockIdx.x, tid = threadIdx.x;
  if (bx < 128) {
    int idx = (bx * 256 + tid) * 8;
    const float* src; int off;
    if (idx < 65536)       { src = Wq; off = idx; }
    else if (idx < 131072) { src = Wk; off = idx - 65536; }
    else if (idx < 196608) { src = Wv; off = idx - 131072; }
    else                   { src = Wm; off = idx - 196608; }
    float4 lo = *(const float4*)(src + off);
    float4 hi = *(const float4*)(src + off + 4);
    union { unsigned u[4]; bf16x8 v; } o;
    o.u[0] = cvt_pk_bf16(lo.x, lo.y); o.u[1] = cvt_pk_bf16(lo.z, lo.w);
    o.u[2] = cvt_pk_bf16(hi.x, hi.y); o.u[3] = cvt_pk_bf16(hi.z, hi.w);
    *(bf16x8*)(Wb + idx) = o.v;
  } else {
    // transpose one 64c x 64p tile: x[b,c,p] fp32 -> xt[b,p,c] bf16
    int bi = bx - 128;
    int b = bi >> 6, rest = bi & 63;
    int ct = (rest & 3) * 64, pt = (rest >> 2) * 64;
    const float* xb = x + ((size_t)(b * NC + ct)) * NP + pt;
    int pr = (tid & 15) * 4, cr = tid >> 4;
#pragma unroll
    for (int i = 0; i < 4; i++) {
      float4 v = *(const float4*)(xb + (size_t)(cr + i * 16) * NP + pr);
      sx[cr + i*16][pr]   = v.x; sx[cr + i*16][pr+1] = v.y;
      sx[cr + i*16][pr+2] = v.z; sx[cr + i*16][pr+3] = v.w;
    }
    __syncthreads();
    int pl = tid >> 3, cc = (tid & 7) * 8;
#pragma unroll
    for (int j = 0; j < 2; j++) {
      int p = pl + j * 32;
      union { unsigned u[4]; bf16x8 v; } o;
#pragma unroll
      for (int u = 0; u < 4; u++)
        o.u[u] = cvt_pk_bf16(sx[cc + 2*u][p], sx[cc + 2*u + 1][p]);
      *(bf16x8*)(xt + ((size_t)b * NP + pt + p) * NC + ct + cc) = o.v;
    }
  }
}

// ---------------- QKV projection GEMM ----------------
__global__ __launch_bounds__(256) void qkv_kernel(
    const unsigned short* __restrict__ Wb,
    const float* __restrict__ bq, const float* __restrict__ bk,
    const float* __restrict__ bv,
    const unsigned short* __restrict__ xt,
    unsigned short* __restrict__ qt, unsigned short* __restrict__ kt,
    unsigned short* __restrict__ vt) {
  int proj = blockIdx.z, b = blockIdx.y, bx = blockIdx.x;
  int ot = (bx & 3) * 64, pt = (bx >> 2) * 64;
  int tid = threadIdx.x, wave = tid >> 6, lane = tid & 63;
  int l15 = lane & 15, quad = lane >> 4;
  int oW = ot + (wave & 1) * 32, pW = pt + (wave >> 1) * 32;
  const unsigned short* W = Wb + (size_t)proj * 65536;
  const float* bias = (proj == 0) ? bq : (proj == 1) ? bk : bv;
  const unsigned short* A0 = W + (size_t)(oW + l15) * NC + quad * 8;
  const unsigned short* B0 = xt + ((size_t)b * NP + pW + l15) * NC + quad * 8;
  f32x4 acc[2][2];
#pragma unroll
  for (int i = 0; i < 2; i++)
#pragma unroll
    for (int j = 0; j < 2; j++) acc[i][j] = (f32x4){0.f, 0.f, 0.f, 0.f};
#pragma unroll
  for (int c0 = 0; c0 < NC; c0 += 32) {
    bf16x8 a0 = *(const bf16x8*)(A0 + c0);
    bf16x8 a1 = *(const bf16x8*)(A0 + 16 * NC + c0);
    bf16x8 b0 = *(const bf16x8*)(B0 + c0);
    bf16x8 b1 = *(const bf16x8*)(B0 + 16 * NC + c0);
    acc[0][0] = __builtin_amdgcn_mfma_f32_16x16x32_bf16(a0, b0, acc[0][0], 0, 0, 0);
    acc[0][1] = __builtin_amdgcn_mfma_f32_16x16x32_bf16(a0, b1, acc[0][1], 0, 0, 0);
    acc[1][0] = __builtin_amdgcn_mfma_f32_16x16x32_bf16(a1, b0, acc[1][0], 0, 0, 0);
    acc[1][1] = __builtin_amdgcn_mfma_f32_16x16x32_bf16(a1, b1, acc[1][1], 0, 0, 0);
  }
  unsigned short* qk = (proj == 0) ? qt : kt;
#pragma unroll
  for (int rh = 0; rh < 2; rh++) {
    int od0 = oW + rh * 16 + quad * 4;             // 4 consecutive o rows
    float b0 = bias[od0], b1 = bias[od0+1], b2 = bias[od0+2], b3 = bias[od0+3];
#pragma unroll
    for (int ch = 0; ch < 2; ch++) {
      float v0 = acc[rh][ch][0] + b0, v1 = acc[rh][ch][1] + b1;
      float v2 = acc[rh][ch][2] + b2, v3 = acc[rh][ch][3] + b3;
      if (proj < 2) {
        int p = pW + ch * 16 + l15;
        int h2 = od0 >> 5, d0 = od0 & 31;
        uint2 pk;
        pk.x = cvt_pk_bf16(v0, v1);
        pk.y = cvt_pk_bf16(v2, v3);
        size_t idx = ((size_t)(b * NHD + h2) * NP + p) * HD + d0;
        *(uint2*)(qk + idx) = pk;
      } else {
        // v -> [b, c=o, p'] bf16; p' = 2*(m&15) + (m>=16) within each 32-tile
        int p2 = pW + 2 * l15 + ch;
        size_t base = ((size_t)b * NC + od0) * NP + p2;
        vt[base]          = f2b1(v0);
        vt[base +     NP] = f2b1(v1);
        vt[base + 2 * NP] = f2b1(v2);
        vt[base + 3 * NP] = f2b1(v3);
      }
    }
  }
}

// ---------------- flash attention ----------------
// grid (64, 8): x = bh (XCD-local K/V), y = n-chunk. Block = 4 waves; wave
// owns 32 q rows (frags a/b). Same-iteration P round-trip (R2/R6-proven).
// K/V register prefetch depth 2 (final over-reads land in adjacent ws bufs).
__global__ __launch_bounds__(256) void attn_kernel(
    const unsigned short* __restrict__ qt, const unsigned short* __restrict__ kt,
    const unsigned short* __restrict__ vt, unsigned short* __restrict__ at) {
  int tid = threadIdx.x, wave = tid >> 6, lane = tid & 63;
  int l15 = lane & 15, quad = lane >> 4;
  int bh = blockIdx.x, b = bh >> 3, h = bh & 7;
  int n0 = blockIdx.y * 128 + wave * 32;
  // per wave: frag a rows at [0,640), frag b rows at [640,1280); row stride 40
  __shared__ __align__(16) unsigned short P[4][1280];
  unsigned short* Pw = &P[wave][0];

  bf16x8 qfa = *(const bf16x8*)(qt + ((size_t)bh * NP + n0 + l15) * HD + quad * 8);
  bf16x8 qfb = *(const bf16x8*)(qt + ((size_t)bh * NP + n0 + 16 + l15) * HD + quad * 8);
  const unsigned short* kp = kt + (size_t)bh * NP * HD + (size_t)l15 * HD + quad * 8;
  const unsigned short* vp = vt + ((size_t)(b * NC + h * HD) + l15) * NP + quad * 8;

  union { unsigned u[4]; bf16x8 v; } ones;
  ones.u[0] = ones.u[1] = ones.u[2] = ones.u[3] = 0x3F803F80u;  // bf16 1.0 x8

  f32x4 oa0 = (f32x4){0.f,0.f,0.f,0.f}, oa1 = (f32x4){0.f,0.f,0.f,0.f};
  f32x4 ob0 = (f32x4){0.f,0.f,0.f,0.f}, ob1 = (f32x4){0.f,0.f,0.f,0.f};
  f32x4 la  = (f32x4){0.f,0.f,0.f,0.f}, lb  = (f32x4){0.f,0.f,0.f,0.f};
  const f32x4 z = (f32x4){0.f,0.f,0.f,0.f};

  // depth-2 prefetch: tiles t (ka/va) and t+1 (kb/vb) resident
  bf16x8 ka0 = *(const bf16x8*)(kp);
  bf16x8 ka1 = *(const bf16x8*)(kp + 16 * HD);
  bf16x8 va0 = *(const bf16x8*)(vp);
  bf16x8 va1 = *(const bf16x8*)(vp + 16 * NP);
  bf16x8 kb0 = *(const bf16x8*)(kp + 32 * HD);
  bf16x8 kb1 = *(const bf16x8*)(kp + 48 * HD);
  bf16x8 vb0 = *(const bf16x8*)(vp + 32);
  bf16x8 vb1 = *(const bf16x8*)(vp + 16 * NP + 32);

  for (int m0 = 0; m0 < NP; m0 += 32) {
    f32x4 s0a = __builtin_amdgcn_mfma_f32_16x16x32_bf16(qfa, ka0, z, 0, 0, 0);
    f32x4 s1a = __builtin_amdgcn_mfma_f32_16x16x32_bf16(qfa, ka1, z, 0, 0, 0);
    f32x4 s0b = __builtin_amdgcn_mfma_f32_16x16x32_bf16(qfb, ka0, z, 0, 0, 0);
    f32x4 s1b = __builtin_amdgcn_mfma_f32_16x16x32_bf16(qfb, ka1, z, 0, 0, 0);
    // prefetch tile t+2 (tail over-reads land in the adjacent ws buffer)
    bf16x8 nk0 = *(const bf16x8*)(kp + (m0 + 64) * HD);
    bf16x8 nk1 = *(const bf16x8*)(kp + (m0 + 80) * HD);
    bf16x8 nv0 = *(const bf16x8*)(vp + m0 + 64);
    bf16x8 nv1 = *(const bf16x8*)(vp + 16 * NP + m0 + 64);
    // p = 2^(s*scale*log2e - 16); constant shift -> exact softmax after /l.
    // cvt_pk packs cols (c, c+16) adjacent; V stored with matching interleave.
#pragma unroll
    for (int r = 0; r < 4; r++) {
      float pa0 = __builtin_amdgcn_exp2f(fmaf(s0a[r], SCLLOG, -16.0f));
      float pa1 = __builtin_amdgcn_exp2f(fmaf(s1a[r], SCLLOG, -16.0f));
      float pb0 = __builtin_amdgcn_exp2f(fmaf(s0b[r], SCLLOG, -16.0f));
      float pb1 = __builtin_amdgcn_exp2f(fmaf(s1b[r], SCLLOG, -16.0f));
      *(unsigned*)(Pw + (quad * 4 + r) * 40 + 2 * l15)       = cvt_pk_bf16(pa0, pa1);
      *(unsigned*)(Pw + 640 + (quad * 4 + r) * 40 + 2 * l15) = cvt_pk_bf16(pb0, pb1);
    }
    // same-wave same-iteration LDS RAW: compiler inserts lgkmcnt wait (proven)
    bf16x8 pfa = *(const bf16x8*)(Pw + l15 * 40 + quad * 8);
    bf16x8 pfb = *(const bf16x8*)(Pw + 640 + l15 * 40 + quad * 8);
    oa0 = __builtin_amdgcn_mfma_f32_16x16x32_bf16(pfa, va0, oa0, 0, 0, 0);
    oa1 = __builtin_amdgcn_mfma_f32_16x16x32_bf16(pfa, va1, oa1, 0, 0, 0);
    ob0 = __builtin_amdgcn_mfma_f32_16x16x32_bf16(pfb, va0, ob0, 0, 0, 0);
    ob1 = __builtin_amdgcn_mfma_f32_16x16x32_bf16(pfb, va1, ob1, 0, 0, 0);
    la  = __builtin_amdgcn_mfma_f32_16x16x32_bf16(pfa, ones.v, la, 0, 0, 0);
    lb  = __builtin_amdgcn_mfma_f32_16x16x32_bf16(pfb, ones.v, lb, 0, 0, 0);
    ka0 = kb0; ka1 = kb1; va0 = vb0; va1 = vb1;
    kb0 = nk0; kb1 = nk1; vb0 = nv0; vb1 = nv1;
  }
  // la/lb rows replicated across the 16 lanes of each row-group (ones-B).
  unsigned short* ab = at + (size_t)b * NP * NC;
#pragma unroll
  for (int r = 0; r < 4; r++) {
    float inva = 1.0f / la[r], invb = 1.0f / lb[r];
    int na = n0 + quad * 4 + r, nb = n0 + 16 + quad * 4 + r;
    ab[(size_t)na * NC + (l15 * 8 + h)]        = f2b1(oa0[r] * inva);
    ab[(size_t)na * NC + ((16 + l15) * 8 + h)] = f2b1(oa1[r] * inva);
    ab[(size_t)nb * NC + (l15 * 8 + h)]        = f2b1(ob0[r] * invb);
    ab[(size_t)nb * NC + ((16 + l15) * 8 + h)] = f2b1(ob1[r] * invb);
  }
}

// ---------------- output projection ----------------
__global__ __launch_bounds__(256) void mproj_kernel(
    const unsigned short* __restrict__ Wmb, const float* __restrict__ bm,
    const unsigned short* __restrict__ at, float* __restrict__ out) {
  int b = blockIdx.y, bx = blockIdx.x;
  int ot = (bx & 3) * 64, pt = (bx >> 2) * 64;
  int tid = threadIdx.x, wave = tid >> 6, lane = tid & 63;
  int l15 = lane & 15, quad = lane >> 4;
  int oW = ot + (wave & 1) * 32, pW = pt + (wave >> 1) * 32;
  const unsigned short* A0 = Wmb + (size_t)(oW + l15) * NC + quad * 8;
  const unsigned short* B0 = at + ((size_t)b * NP + pW + l15) * NC + quad * 8;
  f32x4 acc[2][2];
#pragma unroll
  for (int i = 0; i < 2; i++)
#pragma unroll
    for (int j = 0; j < 2; j++) acc[i][j] = (f32x4){0.f, 0.f, 0.f, 0.f};
#pragma unroll
  for (int c0 = 0; c0 < NC; c0 += 32) {
    bf16x8 a0 = *(const bf16x8*)(A0 + c0);
    bf16x8 a1 = *(const bf16x8*)(A0 + 16 * NC + c0);
    bf16x8 b0 = *(const bf16x8*)(B0 + c0);
    bf16x8 b1 = *(const bf16x8*)(B0 + 16 * NC + c0);
    acc[0][0] = __builtin_amdgcn_mfma_f32_16x16x32_bf16(a0, b0, acc[0][0], 0, 0, 0);
    acc[0][1] = __builtin_amdgcn_mfma_f32_16x16x32_bf16(a0, b1, acc[0][1], 0, 0, 0);
    acc[1][0] = __builtin_amdgcn_mfma_f32_16x16x32_bf16(a1, b0, acc[1][0], 0, 0, 0);
    acc[1][1] = __builtin_amdgcn_mfma_f32_16x16x32_bf16(a1, b1, acc[1][1], 0, 0, 0);
  }
#pragma unroll
  for (int rh = 0; rh < 2; rh++) {
    int od0 = oW + rh * 16 + quad * 4;
    float b0 = bm[od0], b1 = bm[od0+1], b2 = bm[od0+2], b3 = bm[od0+3];
#pragma unroll
    for (int ch = 0; ch < 2; ch++) {
      int p = pW + ch * 16 + l15;
      size_t base = ((size_t)b * NC + od0) * NP + p;
      out[base]          = acc[rh][ch][0] + b0;
      out[base +     NP] = acc[rh][ch][1] + b1;
      out[base + 2 * NP] = acc[rh][ch][2] + b2;
      out[base + 3 * NP] = acc[rh][ch][3] + b3;
    }
  }
}

extern "C" void kernel_launch(void* const* d_in, const int* in_sizes, int n_in,
                              void* d_out, int out_size, void* d_ws, size_t ws_size,
                              hipStream_t stream) {
  (void)in_sizes; (void)n_in; (void)out_size; (void)ws_size;
  const float* x  = (const float*)d_in[0];
  const float* Wq = (const float*)d_in[1];
  const float* bq = (const float*)d_in[2];
  const float* Wk = (const float*)d_in[3];
  const float* bk = (const float*)d_in[4];
  const float* Wv = (const float*)d_in[5];
  const float* bv = (const float*)d_in[6];
  const float* Wm = (const float*)d_in[7];
  const float* bm = (const float*)d_in[8];
  float* out = (float*)d_out;
  char* ws = (char*)d_ws;

  unsigned short* xt = (unsigned short*)(ws);                              // 4 MB
  unsigned short* Wb = (unsigned short*)(ws + (4u << 20));                 // 512 KB
  unsigned short* qt = (unsigned short*)(ws + (4u << 20) + (512u << 10));  // 4 MB
  unsigned short* kt = (unsigned short*)(ws + (8u << 20) + (512u << 10));  // 4 MB
  unsigned short* vt = (unsigned short*)(ws + (12u << 20) + (512u << 10)); // 4 MB
  unsigned short* at = (unsigned short*)(ws + (16u << 20) + (512u << 10)); // 4 MB

  prep_kernel<<<640, 256, 0, stream>>>(Wq, Wk, Wv, Wm, x, Wb, xt);
  qkv_kernel<<<dim3(64, 8, 3), 256, 0, stream>>>(Wb, bq, bk, bv, xt, qt, kt, vt);
  attn_kernel<<<dim3(64, 8), 256, 0, stream>>>(qt, kt, vt, at);
  mproj_kernel<<<dim3(64, 8), 256, 0, stream>>>(Wb + 3 * 65536, bm, at, out);
}

// Round 8
// 137.013 us; speedup vs baseline: 1.0269x; 1.0269x over previous
//
#include <hip/hip_runtime.h>
#include <cstdint>
#include <cstddef>

// SelfAttention: B=8, C=256, H=W=32, HEADS=8, hd=32, N=HW=1024
// Pipeline (all bf16 MFMA 16x16x32, fp32 accum):
//   prep:  W[4] fp32->bf16 ; x [b,c,p] fp32 -> xt [b,p,c] bf16 (LDS transpose)
//   qkv :  q,k -> [b,h,n,d] bf16 ; v -> [b,c,p'] bf16, p' k-interleaved per 32-tile
//   attn:  flash, static-max softmax (2^(s*scale*log2e - 16), exact after 1/l).
//          SPLIT-M: 8-wave block, waves 0-3 do m[0,512), waves 4-7 m[512,1024)
//          for the same q rows; partials combine linearly (static max -> no
//          rescale) through LDS + one __syncthreads. 2x waves/SIMD vs R6.
//          Same-iteration P round-trip per wave (R2/R6-proven, no barriers).
//   mproj: final projection -> d_out fp32
// ws layout: xt 4MB | Wb 512KB | qt 4MB | kt 4MB | vt 4MB | at 4MB  = 20.5 MB

#define NB 8
#define NC 256
#define NP 1024
#define NHD 8
#define HD 32

typedef short bf16x8 __attribute__((ext_vector_type(8)));
typedef float f32x4 __attribute__((ext_vector_type(4)));

// scale * log2(e) : softmax(s/sqrt(32)) computed as 2^(s*SCLLOG - 16)
#define SCLLOG 0.25505654356918f

// hardware packed fp32->bf16 (RNE): D.lo = bf16(a), D.hi = bf16(b)
__device__ __forceinline__ unsigned cvt_pk_bf16(float a, float b) {
  unsigned r;
  asm("v_cvt_pk_bf16_f32 %0, %1, %2" : "=v"(r) : "v"(a), "v"(b));
  return r;
}
__device__ __forceinline__ unsigned short f2b1(float a) {
  return (unsigned short)cvt_pk_bf16(a, a);
}

// ---------------- prep: weight cvt + x transpose ----------------
__global__ __launch_bounds__(256) void prep_kernel(
    const float* __restrict__ Wq, const float* __restrict__ Wk,
    const float* __restrict__ Wv, const float* __restrict__ Wm,
    const float* __restrict__ x, unsigned short* __restrict__ Wb,
    unsigned short* __restrict__ xt) {
  __shared__ float sx[64][65];
  int bx = blockIdx.x, tid = threadIdx.x;
  if (bx < 128) {
    int idx = (bx * 256 + tid) * 8;
    const float* src; int off;
    if (idx < 65536)       { src = Wq; off = idx; }
    else if (idx < 131072) { src = Wk; off = idx - 65536; }
    else if (idx < 196608) { src = Wv; off = idx - 131072; }
    else                   { src = Wm; off = idx - 196608; }
    float4 lo = *(const float4*)(src + off);
    float4 hi = *(const float4*)(src + off + 4);
    union { unsigned u[4]; bf16x8 v; } o;
    o.u[0] = cvt_pk_bf16(lo.x, lo.y); o.u[1] = cvt_pk_bf16(lo.z, lo.w);
    o.u[2] = cvt_pk_bf16(hi.x, hi.y); o.u[3] = cvt_pk_bf16(hi.z, hi.w);
    *(bf16x8*)(Wb + idx) = o.v;
  } else {
    // transpose one 64c x 64p tile: x[b,c,p] fp32 -> xt[b,p,c] bf16
    int bi = bx - 128;
    int b = bi >> 6, rest = bi & 63;
    int ct = (rest & 3) * 64, pt = (rest >> 2) * 64;
    const float* xb = x + ((size_t)(b * NC + ct)) * NP + pt;
    int pr = (tid & 15) * 4, cr = tid >> 4;
#pragma unroll
    for (int i = 0; i < 4; i++) {
      float4 v = *(const float4*)(xb + (size_t)(cr + i * 16) * NP + pr);
      sx[cr + i*16][pr]   = v.x; sx[cr + i*16][pr+1] = v.y;
      sx[cr + i*16][pr+2] = v.z; sx[cr + i*16][pr+3] = v.w;
    }
    __syncthreads();
    int pl = tid >> 3, cc = (tid & 7) * 8;
#pragma unroll
    for (int j = 0; j < 2; j++) {
      int p = pl + j * 32;
      union { unsigned u[4]; bf16x8 v; } o;
#pragma unroll
      for (int u = 0; u < 4; u++)
        o.u[u] = cvt_pk_bf16(sx[cc + 2*u][p], sx[cc + 2*u + 1][p]);
      *(bf16x8*)(xt + ((size_t)b * NP + pt + p) * NC + ct + cc) = o.v;
    }
  }
}

// ---------------- QKV projection GEMM ----------------
__global__ __launch_bounds__(256) void qkv_kernel(
    const unsigned short* __restrict__ Wb,
    const float* __restrict__ bq, const float* __restrict__ bk,
    const float* __restrict__ bv,
    const unsigned short* __restrict__ xt,
    unsigned short* __restrict__ qt, unsigned short* __restrict__ kt,
    unsigned short* __restrict__ vt) {
  int proj = blockIdx.z, b = blockIdx.y, bx = blockIdx.x;
  int ot = (bx & 3) * 64, pt = (bx >> 2) * 64;
  int tid = threadIdx.x, wave = tid >> 6, lane = tid & 63;
  int l15 = lane & 15, quad = lane >> 4;
  int oW = ot + (wave & 1) * 32, pW = pt + (wave >> 1) * 32;
  const unsigned short* W = Wb + (size_t)proj * 65536;
  const float* bias = (proj == 0) ? bq : (proj == 1) ? bk : bv;
  const unsigned short* A0 = W + (size_t)(oW + l15) * NC + quad * 8;
  const unsigned short* B0 = xt + ((size_t)b * NP + pW + l15) * NC + quad * 8;
  f32x4 acc[2][2];
#pragma unroll
  for (int i = 0; i < 2; i++)
#pragma unroll
    for (int j = 0; j < 2; j++) acc[i][j] = (f32x4){0.f, 0.f, 0.f, 0.f};
#pragma unroll
  for (int c0 = 0; c0 < NC; c0 += 32) {
    bf16x8 a0 = *(const bf16x8*)(A0 + c0);
    bf16x8 a1 = *(const bf16x8*)(A0 + 16 * NC + c0);
    bf16x8 b0 = *(const bf16x8*)(B0 + c0);
    bf16x8 b1 = *(const bf16x8*)(B0 + 16 * NC + c0);
    acc[0][0] = __builtin_amdgcn_mfma_f32_16x16x32_bf16(a0, b0, acc[0][0], 0, 0, 0);
    acc[0][1] = __builtin_amdgcn_mfma_f32_16x16x32_bf16(a0, b1, acc[0][1], 0, 0, 0);
    acc[1][0] = __builtin_amdgcn_mfma_f32_16x16x32_bf16(a1, b0, acc[1][0], 0, 0, 0);
    acc[1][1] = __builtin_amdgcn_mfma_f32_16x16x32_bf16(a1, b1, acc[1][1], 0, 0, 0);
  }
  unsigned short* qk = (proj == 0) ? qt : kt;
#pragma unroll
  for (int rh = 0; rh < 2; rh++) {
    int od0 = oW + rh * 16 + quad * 4;             // 4 consecutive o rows
    float b0 = bias[od0], b1 = bias[od0+1], b2 = bias[od0+2], b3 = bias[od0+3];
#pragma unroll
    for (int ch = 0; ch < 2; ch++) {
      float v0 = acc[rh][ch][0] + b0, v1 = acc[rh][ch][1] + b1;
      float v2 = acc[rh][ch][2] + b2, v3 = acc[rh][ch][3] + b3;
      if (proj < 2) {
        int p = pW + ch * 16 + l15;
        int h2 = od0 >> 5, d0 = od0 & 31;
        uint2 pk;
        pk.x = cvt_pk_bf16(v0, v1);
        pk.y = cvt_pk_bf16(v2, v3);
        size_t idx = ((size_t)(b * NHD + h2) * NP + p) * HD + d0;
        *(uint2*)(qk + idx) = pk;
      } else {
        // v -> [b, c=o, p'] bf16; p' = 2*(m&15) + (m>=16) within each 32-tile
        int p2 = pW + 2 * l15 + ch;
        size_t base = ((size_t)b * NC + od0) * NP + p2;
        vt[base]          = f2b1(v0);
        vt[base +     NP] = f2b1(v1);
        vt[base + 2 * NP] = f2b1(v2);
        vt[base + 3 * NP] = f2b1(v3);
      }
    }
  }
}

// ---------------- flash attention (split-m) ----------------
// grid (8, 64); block = 512 threads = 8 waves. wsub = wave&3 picks the 32
// q rows (n0 = bx*128 + wsub*32); half = wave>>2 picks the m range
// ([0,512) or [512,1024), 16 tiles each). Static max => partials combine
// linearly: half-1 waves dump (o, l) to LDS, half-0 waves add and finish.
// Per-tile body is R6-verbatim (same-iteration P round-trip, depth-1 prefetch).
__global__ __launch_bounds__(512) void attn_kernel(
    const unsigned short* __restrict__ qt, const unsigned short* __restrict__ kt,
    const unsigned short* __restrict__ vt, unsigned short* __restrict__ at) {
  int tid = threadIdx.x, wave = tid >> 6, lane = tid & 63;
  int l15 = lane & 15, quad = lane >> 4;
  int half = wave >> 2, wsub = wave & 3;
  int bh = blockIdx.y, b = bh >> 3, h = bh & 7;
  int n0 = blockIdx.x * 128 + wsub * 32;
  // per wave: frag a rows at [0,640), frag b rows at [640,1280); row stride 40
  __shared__ __align__(16) unsigned short P[8][1280];
  __shared__ float Comb[4][64][25];       // [wsub][lane][24 floats + 1 pad]
  unsigned short* Pw = &P[wave][0];

  bf16x8 qfa = *(const bf16x8*)(qt + ((size_t)bh * NP + n0 + l15) * HD + quad * 8);
  bf16x8 qfb = *(const bf16x8*)(qt + ((size_t)bh * NP + n0 + 16 + l15) * HD + quad * 8);
  const unsigned short* kp = kt + (size_t)bh * NP * HD + (size_t)l15 * HD + quad * 8;
  const unsigned short* vp = vt + ((size_t)(b * NC + h * HD) + l15) * NP + quad * 8;

  union { unsigned u[4]; bf16x8 v; } ones;
  ones.u[0] = ones.u[1] = ones.u[2] = ones.u[3] = 0x3F803F80u;  // bf16 1.0 x8

  f32x4 oa0 = (f32x4){0.f,0.f,0.f,0.f}, oa1 = (f32x4){0.f,0.f,0.f,0.f};
  f32x4 ob0 = (f32x4){0.f,0.f,0.f,0.f}, ob1 = (f32x4){0.f,0.f,0.f,0.f};
  f32x4 la  = (f32x4){0.f,0.f,0.f,0.f}, lb  = (f32x4){0.f,0.f,0.f,0.f};
  const f32x4 z = (f32x4){0.f,0.f,0.f,0.f};

  int mbase = half * 512;
  bf16x8 kf0 = *(const bf16x8*)(kp + mbase * HD);
  bf16x8 kf1 = *(const bf16x8*)(kp + (mbase + 16) * HD);
  bf16x8 vf0 = *(const bf16x8*)(vp + mbase);
  bf16x8 vf1 = *(const bf16x8*)(vp + 16 * NP + mbase);

  for (int m0 = mbase; m0 < mbase + 512; m0 += 32) {
    f32x4 s0a = __builtin_amdgcn_mfma_f32_16x16x32_bf16(qfa, kf0, z, 0, 0, 0);
    f32x4 s1a = __builtin_amdgcn_mfma_f32_16x16x32_bf16(qfa, kf1, z, 0, 0, 0);
    f32x4 s0b = __builtin_amdgcn_mfma_f32_16x16x32_bf16(qfb, kf0, z, 0, 0, 0);
    f32x4 s1b = __builtin_amdgcn_mfma_f32_16x16x32_bf16(qfb, kf1, z, 0, 0, 0);
    // prefetch next tile (tail over-read lands in the adjacent ws buffer)
    bf16x8 nk0 = *(const bf16x8*)(kp + (m0 + 32) * HD);
    bf16x8 nk1 = *(const bf16x8*)(kp + (m0 + 48) * HD);
    bf16x8 nv0 = *(const bf16x8*)(vp + m0 + 32);
    bf16x8 nv1 = *(const bf16x8*)(vp + 16 * NP + m0 + 32);
    // p = 2^(s*scale*log2e - 16); constant shift -> exact softmax after /l.
    // cvt_pk packs cols (c, c+16) adjacent; V stored with matching interleave.
#pragma unroll
    for (int r = 0; r < 4; r++) {
      float pa0 = __builtin_amdgcn_exp2f(fmaf(s0a[r], SCLLOG, -16.0f));
      float pa1 = __builtin_amdgcn_exp2f(fmaf(s1a[r], SCLLOG, -16.0f));
      float pb0 = __builtin_amdgcn_exp2f(fmaf(s0b[r], SCLLOG, -16.0f));
      float pb1 = __builtin_amdgcn_exp2f(fmaf(s1b[r], SCLLOG, -16.0f));
      *(unsigned*)(Pw + (quad * 4 + r) * 40 + 2 * l15)       = cvt_pk_bf16(pa0, pa1);
      *(unsigned*)(Pw + 640 + (quad * 4 + r) * 40 + 2 * l15) = cvt_pk_bf16(pb0, pb1);
    }
    // same-wave same-iteration LDS RAW: compiler inserts lgkmcnt wait (proven)
    bf16x8 pfa = *(const bf16x8*)(Pw + l15 * 40 + quad * 8);
    bf16x8 pfb = *(const bf16x8*)(Pw + 640 + l15 * 40 + quad * 8);
    oa0 = __builtin_amdgcn_mfma_f32_16x16x32_bf16(pfa, vf0, oa0, 0, 0, 0);
    oa1 = __builtin_amdgcn_mfma_f32_16x16x32_bf16(pfa, vf1, oa1, 0, 0, 0);
    ob0 = __builtin_amdgcn_mfma_f32_16x16x32_bf16(pfb, vf0, ob0, 0, 0, 0);
    ob1 = __builtin_amdgcn_mfma_f32_16x16x32_bf16(pfb, vf1, ob1, 0, 0, 0);
    la  = __builtin_amdgcn_mfma_f32_16x16x32_bf16(pfa, ones.v, la, 0, 0, 0);
    lb  = __builtin_amdgcn_mfma_f32_16x16x32_bf16(pfb, ones.v, lb, 0, 0, 0);
    kf0 = nk0; kf1 = nk1; vf0 = nv0; vf1 = nv1;
  }

  // ---- combine halves ----
  if (half == 1) {
    float* C = &Comb[wsub][lane][0];
#pragma unroll
    for (int r = 0; r < 4; r++) {
      C[r]      = oa0[r];  C[4 + r]  = oa1[r];
      C[8 + r]  = ob0[r];  C[12 + r] = ob1[r];
      C[16 + r] = la[r];   C[20 + r] = lb[r];
    }
  }
  __syncthreads();
  if (half == 0) {
    const float* C = &Comb[wsub][lane][0];
#pragma unroll
    for (int r = 0; r < 4; r++) {
      oa0[r] += C[r];      oa1[r] += C[4 + r];
      ob0[r] += C[8 + r];  ob1[r] += C[12 + r];
      la[r]  += C[16 + r]; lb[r]  += C[20 + r];
    }
    // la/lb rows replicated across the 16 lanes of each row-group (ones-B).
    unsigned short* ab = at + (size_t)b * NP * NC;
#pragma unroll
    for (int r = 0; r < 4; r++) {
      float inva = 1.0f / la[r], invb = 1.0f / lb[r];
      int na = n0 + quad * 4 + r, nb = n0 + 16 + quad * 4 + r;
      ab[(size_t)na * NC + (l15 * 8 + h)]        = f2b1(oa0[r] * inva);
      ab[(size_t)na * NC + ((16 + l15) * 8 + h)] = f2b1(oa1[r] * inva);
      ab[(size_t)nb * NC + (l15 * 8 + h)]        = f2b1(ob0[r] * invb);
      ab[(size_t)nb * NC + ((16 + l15) * 8 + h)] = f2b1(ob1[r] * invb);
    }
  }
}

// ---------------- output projection ----------------
__global__ __launch_bounds__(256) void mproj_kernel(
    const unsigned short* __restrict__ Wmb, const float* __restrict__ bm,
    const unsigned short* __restrict__ at, float* __restrict__ out) {
  int b = blockIdx.y, bx = blockIdx.x;
  int ot = (bx & 3) * 64, pt = (bx >> 2) * 64;
  int tid = threadIdx.x, wave = tid >> 6, lane = tid & 63;
  int l15 = lane & 15, quad = lane >> 4;
  int oW = ot + (wave & 1) * 32, pW = pt + (wave >> 1) * 32;
  const unsigned short* A0 = Wmb + (size_t)(oW + l15) * NC + quad * 8;
  const unsigned short* B0 = at + ((size_t)b * NP + pW + l15) * NC + quad * 8;
  f32x4 acc[2][2];
#pragma unroll
  for (int i = 0; i < 2; i++)
#pragma unroll
    for (int j = 0; j < 2; j++) acc[i][j] = (f32x4){0.f, 0.f, 0.f, 0.f};
#pragma unroll
  for (int c0 = 0; c0 < NC; c0 += 32) {
    bf16x8 a0 = *(const bf16x8*)(A0 + c0);
    bf16x8 a1 = *(const bf16x8*)(A0 + 16 * NC + c0);
    bf16x8 b0 = *(const bf16x8*)(B0 + c0);
    bf16x8 b1 = *(const bf16x8*)(B0 + 16 * NC + c0);
    acc[0][0] = __builtin_amdgcn_mfma_f32_16x16x32_bf16(a0, b0, acc[0][0], 0, 0, 0);
    acc[0][1] = __builtin_amdgcn_mfma_f32_16x16x32_bf16(a0, b1, acc[0][1], 0, 0, 0);
    acc[1][0] = __builtin_amdgcn_mfma_f32_16x16x32_bf16(a1, b0, acc[1][0], 0, 0, 0);
    acc[1][1] = __builtin_amdgcn_mfma_f32_16x16x32_bf16(a1, b1, acc[1][1], 0, 0, 0);
  }
#pragma unroll
  for (int rh = 0; rh < 2; rh++) {
    int od0 = oW + rh * 16 + quad * 4;
    float b0 = bm[od0], b1 = bm[od0+1], b2 = bm[od0+2], b3 = bm[od0+3];
#pragma unroll
    for (int ch = 0; ch < 2; ch++) {
      int p = pW + ch * 16 + l15;
      size_t base = ((size_t)b * NC + od0) * NP + p;
      out[base]          = acc[rh][ch][0] + b0;
      out[base +     NP] = acc[rh][ch][1] + b1;
      out[base + 2 * NP] = acc[rh][ch][2] + b2;
      out[base + 3 * NP] = acc[rh][ch][3] + b3;
    }
  }
}

extern "C" void kernel_launch(void* const* d_in, const int* in_sizes, int n_in,
                              void* d_out, int out_size, void* d_ws, size_t ws_size,
                              hipStream_t stream) {
  (void)in_sizes; (void)n_in; (void)out_size; (void)ws_size;
  const float* x  = (const float*)d_in[0];
  const float* Wq = (const float*)d_in[1];
  const float* bq = (const float*)d_in[2];
  const float* Wk = (const float*)d_in[3];
  const float* bk = (const float*)d_in[4];
  const float* Wv = (const float*)d_in[5];
  const float* bv = (const float*)d_in[6];
  const float* Wm = (const float*)d_in[7];
  const float* bm = (const float*)d_in[8];
  float* out = (float*)d_out;
  char* ws = (char*)d_ws;

  unsigned short* xt = (unsigned short*)(ws);                              // 4 MB
  unsigned short* Wb = (unsigned short*)(ws + (4u << 20));                 // 512 KB
  unsigned short* qt = (unsigned short*)(ws + (4u << 20) + (512u << 10));  // 4 MB
  unsigned short* kt = (unsigned short*)(ws + (8u << 20) + (512u << 10));  // 4 MB
  unsigned short* vt = (unsigned short*)(ws + (12u << 20) + (512u << 10)); // 4 MB
  unsigned short* at = (unsigned short*)(ws + (16u << 20) + (512u << 10)); // 4 MB

  prep_kernel<<<640, 256, 0, stream>>>(Wq, Wk, Wv, Wm, x, Wb, xt);
  qkv_kernel<<<dim3(64, 8, 3), 256, 0, stream>>>(Wb, bq, bk, bv, xt, qt, kt, vt);
  attn_kernel<<<dim3(8, 64), 512, 0, stream>>>(qt, kt, vt, at);
  mproj_kernel<<<dim3(64, 8), 256, 0, stream>>>(Wb + 3 * 65536, bm, at, out);
}